// Round 1
// 333.791 us; speedup vs baseline: 1.0701x; 1.0701x over previous
//
#include <hip/hip_runtime.h>

#define DF 64
#define BSH 8              // bucket = dst >> 8  (256 dst per bucket)
#define BW  256

typedef unsigned short u16;
typedef unsigned int u32;
typedef __attribute__((ext_vector_type(8))) short short8;
typedef __attribute__((ext_vector_type(4))) float f32x4;

__device__ __forceinline__ float bf2f(u16 u) { return __uint_as_float(((u32)u) << 16); }
__device__ __forceinline__ u16 f2bf(float f) {
  u32 v = __float_as_uint(f);
  return (u16)((v + 0x7FFFu + ((v >> 16) & 1u)) >> 16);
}

// ============== bucket-sort CSR build (atomic-free globals) ==============

__global__ __launch_bounds__(256) void prehist(const int* __restrict__ ei,
                                               int* __restrict__ gh, int E, int NB) {
  __shared__ int lh[512];
  for (int t = threadIdx.x; t < NB; t += 256) lh[t] = 0;
  __syncthreads();
  int e0 = blockIdx.x * 1024;
#pragma unroll
  for (int j = 0; j < 4; j++) {
    int e = e0 + j * 256 + threadIdx.x;
    if (e < E) atomicAdd(&lh[ei[E + e] >> BSH], 1);
  }
  __syncthreads();
  for (int t = threadIdx.x; t < NB; t += 256)
    gh[(size_t)blockIdx.x * NB + t] = lh[t];
}

__global__ __launch_bounds__(256) void scanA(int* __restrict__ gh, int* __restrict__ btot,
                                             int nblk, int NB) {
  int c = blockIdx.x;
  __shared__ int sc[256];
  int carry = 0;
  for (int b0 = 0; b0 < nblk; b0 += 256) {
    int b = b0 + threadIdx.x;
    int orig = (b < nblk) ? gh[(size_t)b * NB + c] : 0;
    int v = orig;
    sc[threadIdx.x] = v;
    __syncthreads();
    for (int off = 1; off < 256; off <<= 1) {
      int o = threadIdx.x >= off ? sc[threadIdx.x - off] : 0;
      __syncthreads();
      v += o;
      sc[threadIdx.x] = v;
      __syncthreads();
    }
    int ctot = sc[255];
    if (b < nblk) gh[(size_t)b * NB + c] = carry + v - orig;
    carry += ctot;
    __syncthreads();
  }
  if (threadIdx.x == 0) btot[c] = carry;
}

__global__ __launch_bounds__(256) void scanB(const int* __restrict__ btot,
                                             int* __restrict__ bstart,
                                             int* __restrict__ rowptr, int NB, int n, int E) {
  __shared__ int sc[256];
  int base = threadIdx.x * 4;
  int c[4], s = 0;
#pragma unroll
  for (int j = 0; j < 4; j++) {
    int idx = base + j;
    c[j] = idx < NB ? btot[idx] : 0;
    s += c[j];
  }
  int v = s;
  sc[threadIdx.x] = v;
  __syncthreads();
  for (int off = 1; off < 256; off <<= 1) {
    int o = threadIdx.x >= off ? sc[threadIdx.x - off] : 0;
    __syncthreads();
    v += o;
    sc[threadIdx.x] = v;
    __syncthreads();
  }
  int run = v - s;
#pragma unroll
  for (int j = 0; j < 4; j++) {
    int idx = base + j;
    if (idx <= NB) bstart[idx] = run;
    run += c[j];
  }
  if (threadIdx.x == 0) rowptr[n] = E;   // sentinel (pass2 rewrites same value if n%256!=0)
}

// bin edges into dst-buckets; 8B records {dl | src<<8, w_fp32}
__global__ __launch_bounds__(256) void pass1(const int* __restrict__ ei,
                                             const float* __restrict__ w,
                                             const int* __restrict__ gh,
                                             const int* __restrict__ bstart,
                                             int2* __restrict__ pk1, int E, int NB) {
  __shared__ int lh[512];
  __shared__ int lbase[512];
  for (int t = threadIdx.x; t < NB; t += 256) lh[t] = 0;
  __syncthreads();
  int e0 = blockIdx.x * 1024;
  int s[4], d[4], r[4];
  float wv[4];
#pragma unroll
  for (int j = 0; j < 4; j++) {
    int e = e0 + j * 256 + threadIdx.x;
    if (e < E) {
      s[j] = ei[e];
      d[j] = ei[E + e];
      wv[j] = w[e];
      r[j] = atomicAdd(&lh[d[j] >> BSH], 1);
    }
  }
  __syncthreads();
  for (int t = threadIdx.x; t < NB; t += 256)
    lbase[t] = bstart[t] + gh[(size_t)blockIdx.x * NB + t];
  __syncthreads();
#pragma unroll
  for (int j = 0; j < 4; j++) {
    int e = e0 + j * 256 + threadIdx.x;
    if (e < E)
      pk1[lbase[d[j] >> BSH] + r[j]] =
          make_int2((d[j] & 255) | (s[j] << 8), __float_as_int(wv[j]));
  }
}

// per-bucket counting sort (LDS) -> pk2 {src | dl<<17, w_fp32}; emit dinv + per-node rowptr
__global__ __launch_bounds__(256) void pass2(const int2* __restrict__ pk1,
                                             const int* __restrict__ bstart,
                                             int2* __restrict__ pk2,
                                             float* __restrict__ dinv,
                                             int* __restrict__ rowptr, int n) {
  int c = blockIdx.x;
  int dbase = c << BSH;
  __shared__ int h[BW];
  __shared__ float dg[BW];
  __shared__ int sc[BW];
  __shared__ int cur[BW];
  h[threadIdx.x] = 0;
  dg[threadIdx.x] = 0.f;
  __syncthreads();
  int e0 = bstart[c], e1 = bstart[c + 1];
  for (int e = e0 + threadIdx.x; e < e1; e += 256) {
    int2 p = pk1[e];
    int dl = p.x & 255;
    atomicAdd(&h[dl], 1);
    atomicAdd(&dg[dl], __int_as_float(p.y));
  }
  __syncthreads();
  int own = h[threadIdx.x];
  int v = own;
  sc[threadIdx.x] = v;
  __syncthreads();
  for (int off = 1; off < 256; off <<= 1) {
    int o = threadIdx.x >= off ? sc[threadIdx.x - off] : 0;
    __syncthreads();
    v += o;
    sc[threadIdx.x] = v;
    __syncthreads();
  }
  int start = e0 + v - own;
  cur[threadIdx.x] = start;
  int i = dbase + threadIdx.x;
  if (i < n) dinv[i] = rsqrtf(dg[threadIdx.x] + 1.0f);   // self-loop +1
  if (i <= n) rowptr[i] = start;                          // per-node CSR pointer
  __syncthreads();
  for (int e = e0 + threadIdx.x; e < e1; e += 256) {
    int2 p = pk1[e];
    int dl = p.x & 255;
    int slot = atomicAdd(&cur[dl], 1);
    pk2[slot] = make_int2((p.x >> 8) | (dl << 17), p.y);
  }
}

// ================= compute =================

// B fragment for MFMA 16x16x32: B[k = k0+j][col], bf16-RNE from fp32 W
__device__ __forceinline__ short8 bfrag(const float* __restrict__ W, int k0, int col) {
  short8 b;
#pragma unroll
  for (int j = 0; j < 8; j++) b[j] = (short)f2bf(W[(k0 + j) * DF + col]);
  return b;
}

// MFMA GEMM: xl' = bf16( (bf16(A) @ bf16(W)) * dinv_row )   (src-side dinv folded in)
__global__ __launch_bounds__(256) void gemm_init(const float* __restrict__ A,
                                                 const float* __restrict__ W,
                                                 const float* __restrict__ dinv,
                                                 u16* __restrict__ xl, int n, int tiles) {
  int lane = threadIdx.x & 63;
  int m = lane & 15, quad = lane >> 4;
  int wid = blockIdx.x * 4 + (threadIdx.x >> 6);
  int nw = gridDim.x * 4;
  short8 B0[4], B1[4];
#pragma unroll
  for (int ft = 0; ft < 4; ft++) {
    B0[ft] = bfrag(W, quad * 8, ft * 16 + m);
    B1[ft] = bfrag(W, 32 + quad * 8, ft * 16 + m);
  }
  for (int t = wid; t < tiles; t += nw) {
    int row0 = t * 16;
    int r = row0 + m;
    if (r >= n) r = n - 1;
    const float* ap = A + (size_t)r * DF + quad * 8;
    float4 u0 = *(const float4*)ap;
    float4 u1 = *(const float4*)(ap + 4);
    float4 u2 = *(const float4*)(ap + 32);
    float4 u3 = *(const float4*)(ap + 36);
    short8 a0, a1;
    a0[0]=(short)f2bf(u0.x); a0[1]=(short)f2bf(u0.y); a0[2]=(short)f2bf(u0.z); a0[3]=(short)f2bf(u0.w);
    a0[4]=(short)f2bf(u1.x); a0[5]=(short)f2bf(u1.y); a0[6]=(short)f2bf(u1.z); a0[7]=(short)f2bf(u1.w);
    a1[0]=(short)f2bf(u2.x); a1[1]=(short)f2bf(u2.y); a1[2]=(short)f2bf(u2.z); a1[3]=(short)f2bf(u2.w);
    a1[4]=(short)f2bf(u3.x); a1[5]=(short)f2bf(u3.y); a1[6]=(short)f2bf(u3.z); a1[7]=(short)f2bf(u3.w);
    f32x4 c[4];
#pragma unroll
    for (int ft = 0; ft < 4; ft++) c[ft] = (f32x4){0.f, 0.f, 0.f, 0.f};
#pragma unroll
    for (int ft = 0; ft < 4; ft++) {
      c[ft] = __builtin_amdgcn_mfma_f32_16x16x32_bf16(a0, B0[ft], c[ft], 0, 0, 0);
      c[ft] = __builtin_amdgcn_mfma_f32_16x16x32_bf16(a1, B1[ft], c[ft], 0, 0, 0);
    }
    float dd[4];
#pragma unroll
    for (int reg = 0; reg < 4; reg++) {
      int r2 = row0 + quad * 4 + reg;
      dd[reg] = (r2 < n) ? dinv[r2] : 0.f;
    }
#pragma unroll
    for (int ft = 0; ft < 4; ft++)
#pragma unroll
      for (int reg = 0; reg < 4; reg++) {
        int r2 = row0 + quad * 4 + reg;
        if (r2 < n)
          xl[(size_t)r2 * DF + ft * 16 + m] = f2bf(c[ft][reg] * dd[reg]);
      }
  }
}

// MFMA GEMM with BN+PReLU fused into A-load; same dinv-folded bf16 output
__global__ __launch_bounds__(256) void gemm_bn_init(const float* __restrict__ accin,
                                                    const float* __restrict__ stats,
                                                    const float* __restrict__ alpha_p,
                                                    const float* __restrict__ W,
                                                    const float* __restrict__ dinv,
                                                    u16* __restrict__ xl, int n, int tiles) {
  int lane = threadIdx.x & 63;
  int m = lane & 15, quad = lane >> 4;
  int wid = blockIdx.x * 4 + (threadIdx.x >> 6);
  int nw = gridDim.x * 4;
  short8 B0[4], B1[4];
#pragma unroll
  for (int ft = 0; ft < 4; ft++) {
    B0[ft] = bfrag(W, quad * 8, ft * 16 + m);
    B1[ft] = bfrag(W, 32 + quad * 8, ft * 16 + m);
  }
  float s0[8], t0[8], s1[8], t1[8];
#pragma unroll
  for (int j = 0; j < 8; j++) {
    s0[j] = stats[128 + quad * 8 + j];
    t0[j] = stats[192 + quad * 8 + j];
    s1[j] = stats[128 + 32 + quad * 8 + j];
    t1[j] = stats[192 + 32 + quad * 8 + j];
  }
  float al = alpha_p[0];
  for (int t = wid; t < tiles; t += nw) {
    int row0 = t * 16;
    int r = row0 + m;
    if (r >= n) r = n - 1;
    const float* ap = accin + (size_t)r * DF + quad * 8;
    float h0[8], h1[8];
#pragma unroll
    for (int j = 0; j < 8; j++) { h0[j] = ap[j]; h1[j] = ap[32 + j]; }
    short8 a0, a1;
#pragma unroll
    for (int j = 0; j < 8; j++) {
      float y0 = h0[j] * s0[j] + t0[j];
      y0 = (y0 >= 0.f) ? y0 : al * y0;
      a0[j] = (short)f2bf(y0);
      float y1 = h1[j] * s1[j] + t1[j];
      y1 = (y1 >= 0.f) ? y1 : al * y1;
      a1[j] = (short)f2bf(y1);
    }
    f32x4 c[4];
#pragma unroll
    for (int ft = 0; ft < 4; ft++) c[ft] = (f32x4){0.f, 0.f, 0.f, 0.f};
#pragma unroll
    for (int ft = 0; ft < 4; ft++) {
      c[ft] = __builtin_amdgcn_mfma_f32_16x16x32_bf16(a0, B0[ft], c[ft], 0, 0, 0);
      c[ft] = __builtin_amdgcn_mfma_f32_16x16x32_bf16(a1, B1[ft], c[ft], 0, 0, 0);
    }
    float dd[4];
#pragma unroll
    for (int reg = 0; reg < 4; reg++) {
      int r2 = row0 + quad * 4 + reg;
      dd[reg] = (r2 < n) ? dinv[r2] : 0.f;
    }
#pragma unroll
    for (int ft = 0; ft < 4; ft++)
#pragma unroll
      for (int reg = 0; reg < 4; reg++) {
        int r2 = row0 + quad * 4 + reg;
        if (r2 < n)
          xl[(size_t)r2 * DF + ft * 16 + m] = f2bf(c[ft][reg] * dd[reg]);
      }
  }
}

// owner-computes segmented aggregation: wave = 8 exclusive dst rows (via rowptr).
// register accumulation, NO global atomics on acc; self-loop + bias + dinv_d folded;
// BN partial stats computed in-register (stats_kernel eliminated).
__global__ __launch_bounds__(256) void edge_agg3(const int2* __restrict__ pk,
                                                 const int* __restrict__ rowptr,
                                                 const u16* __restrict__ xl,
                                                 const float* __restrict__ dinv,
                                                 const float* __restrict__ bias,
                                                 float* __restrict__ acc,
                                                 float* __restrict__ statp, int n) {
  int lane = threadIdx.x & 63;
  int wsub = threadIdx.x >> 6;
  int r0 = (blockIdx.x * 4 + wsub) * 8;
  int ru = __builtin_amdgcn_readfirstlane(r0);
  float bl = bias[lane];
  float ssum = 0.f, ssq = 0.f;
  if (ru < n) {
    int rend = min(ru + 8, n);
    int eb0 = __builtin_amdgcn_readfirstlane(rowptr[ru]);
    int cnt = __builtin_amdgcn_readfirstlane(rowptr[rend]) - eb0;
    const int2* __restrict__ pw = pk + eb0;
    int row = ru;
    int curdl = ru & 255;                 // 8 rows always within one 256-dst bucket
    float dv = dinv[row];
    float a = bf2f(xl[((size_t)row << 6) | lane]);   // self-loop: xl' already has dinv_d
    for (int base = 0; base < cnt; base += 16) {
      int sj[16], dj[16];
      float vj[16];
#pragma unroll
      for (int j = 0; j < 16; j++) {
        int e = base + j;
        int ec = e < cnt ? e : cnt - 1;   // clamped tail: dl repeats, weight zeroed
        int2 p = pw[ec];                  // wave-uniform -> scalar loads
        sj[j] = p.x & 0x1FFFF;
        dj[j] = (p.x >> 17) & 255;
        vj[j] = (e < cnt) ? __int_as_float(p.y) : 0.f;
      }
      float xb[16];
#pragma unroll
      for (int j = 0; j < 16; j++)
        xb[j] = bf2f(xl[((size_t)sj[j] << 6) | lane]);  // 16 independent 128B gathers
#pragma unroll
      for (int j = 0; j < 16; j++) {
        while (dj[j] != curdl) {          // wave-uniform row advance (handles empty rows)
          float val = fmaf(a, dv, bl);
          acc[((size_t)row << 6) | lane] = val;
          ssum += val;
          ssq += val * val;
          row++;
          curdl = (curdl + 1) & 255;
          dv = dinv[row];
          a = bf2f(xl[((size_t)row << 6) | lane]);
        }
        a = fmaf(vj[j], xb[j], a);        // w is raw fp32 (val_kernel eliminated)
      }
    }
    for (;;) {                            // flush remaining rows (incl. trailing empties)
      float val = fmaf(a, dv, bl);
      acc[((size_t)row << 6) | lane] = val;
      ssum += val;
      ssq += val * val;
      row++;
      if (row >= rend) break;
      dv = dinv[row];
      a = bf2f(xl[((size_t)row << 6) | lane]);
    }
  }
  __shared__ float ls[4][DF], lss[4][DF];
  ls[wsub][lane] = ssum;
  lss[wsub][lane] = ssq;
  __syncthreads();
  if (threadIdx.x < DF) {
    int f = threadIdx.x;
    float t1 = ls[0][f] + ls[1][f] + ls[2][f] + ls[3][f];
    float t2 = lss[0][f] + lss[1][f] + lss[2][f] + lss[3][f];
    int slot = (blockIdx.x & 63) * 128;   // 64-way spread kills same-line contention
    unsafeAtomicAdd(&statp[slot + f], t1);
    unsafeAtomicAdd(&statp[slot + DF + f], t2);
  }
}

__global__ void finalize_stats(const float* __restrict__ statp, float* __restrict__ stats,
                               const float* __restrict__ gamma,
                               const float* __restrict__ beta, int n) {
  int f = threadIdx.x;
  if (f >= DF) return;
  float s = 0.f, ss = 0.f;
#pragma unroll 4
  for (int c = 0; c < 64; c++) {
    s += statp[c * 128 + f];
    ss += statp[c * 128 + DF + f];
  }
  float mean = s / n;
  float var = ss / n - mean * mean;
  float rstd = rsqrtf(var + 1e-5f);
  float sc = gamma[f] * rstd;
  stats[128 + f] = sc;
  stats[192 + f] = beta[f] - mean * sc;
}

__global__ void bnapply(const float* __restrict__ acc, const float* __restrict__ stats,
                        const float* __restrict__ alpha_p, float* __restrict__ outb, int n) {
  int i = blockIdx.x * 4 + (threadIdx.x >> 6);
  if (i >= n) return;
  int f = threadIdx.x & 63;
  float y = acc[(size_t)i * DF + f] * stats[128 + f] + stats[192 + f];
  float a = alpha_p[0];
  y = (y >= 0.f) ? y : a * y;
  outb[(size_t)i * DF + f] = y;
}

extern "C" void kernel_launch(void* const* d_in, const int* in_sizes, int n_in,
                              void* d_out, int out_size, void* d_ws, size_t ws_size,
                              hipStream_t stream) {
  const float* x  = (const float*)d_in[0];
  const int* ei   = (const int*)d_in[1];
  const float* w  = (const float*)d_in[2];
  const float* W1 = (const float*)d_in[3];
  const float* b1 = (const float*)d_in[4];
  const float* g1 = (const float*)d_in[5];
  const float* be1= (const float*)d_in[6];
  const float* al1= (const float*)d_in[7];
  const float* W2 = (const float*)d_in[8];
  const float* b2 = (const float*)d_in[9];
  const float* g2 = (const float*)d_in[10];
  const float* be2= (const float*)d_in[11];
  const float* al2= (const float*)d_in[12];
  float* out = (float*)d_out;

  const int n = in_sizes[0] / DF;
  const int E = in_sizes[2];
  const size_t na = ((size_t)n + 255) & ~(size_t)255;
  const int NB = (n + BW - 1) >> BSH;
  const int nblk1 = (E + 1023) / 1024;
  const size_t ghsz = (((size_t)nblk1 * NB) + 3) & ~(size_t)3;
  const int tiles = (n + 15) / 16;

  // ---- workspace layout (4-byte units; int2 arrays 8B-aligned) ----
  float* wsf = (float*)d_ws;
  float* stats1 = wsf;                          // 256
  float* stats2 = stats1 + 256;                 // 256
  float* statp1 = stats2 + 256;                 // 8192 (64 spread copies x 128)
  float* statp2 = statp1 + 8192;                // 8192
  int*   btot   = (int*)(statp2 + 8192);        // 512
  int*   bstart = btot + 512;                   // 512 (NB+1 used)
  int*   rowptr = bstart + 512;                 // na + 4 (n+1 used)
  float* dinv   = (float*)(rowptr + na + 4);    // na
  int*   gh     = (int*)(dinv + na);            // ghsz
  int2*  pk2    = (int2*)(gh + ghsz);           // E+64 records (8B each)
  int*   U      = (int*)(pk2 + (E + 64));       // overlay: pk1 (2E) | XL16+ACC
  int2*  pk1    = (int2*)U;
  u16*   XL16   = (u16*)U;                      // na*64 bf16 (after pass2)
  float* ACC    = (float*)(U + na * 32);        // na*64 fp32

  const int nb_nodes = (n + 3) / 4;
  const int nb_gemm  = 512;
  const int nb_agg   = (n + 31) / 32;

  hipMemsetAsync(stats1, 0, (512 + 16384) * sizeof(float), stream);

  // ---- CSR build (bucket sort, 8B records, per-node rowptr) ----
  prehist<<<nblk1, 256, 0, stream>>>(ei, gh, E, NB);
  scanA<<<NB, 256, 0, stream>>>(gh, btot, nblk1, NB);
  scanB<<<1, 256, 0, stream>>>(btot, bstart, rowptr, NB, n, E);
  pass1<<<nblk1, 256, 0, stream>>>(ei, w, gh, bstart, pk1, E, NB);
  pass2<<<NB, 256, 0, stream>>>(pk1, bstart, pk2, dinv, rowptr, n);

  // ---- layer 1 ----
  gemm_init<<<nb_gemm, 256, 0, stream>>>(x, W1, dinv, XL16, n, tiles);
  edge_agg3<<<nb_agg, 256, 0, stream>>>(pk2, rowptr, XL16, dinv, b1, ACC, statp1, n);
  finalize_stats<<<1, 64, 0, stream>>>(statp1, stats1, g1, be1, n);

  // ---- layer 2 ----
  gemm_bn_init<<<nb_gemm, 256, 0, stream>>>(ACC, stats1, al1, W2, dinv, XL16, n, tiles);
  edge_agg3<<<nb_agg, 256, 0, stream>>>(pk2, rowptr, XL16, dinv, b2, ACC, statp2, n);
  finalize_stats<<<1, 64, 0, stream>>>(statp2, stats2, g2, be2, n);
  bnapply<<<nb_nodes, 256, 0, stream>>>(ACC, stats2, al2, out, n);
}